// Round 8
// baseline (27.472 us; speedup 1.0000x reference)
//
#include <hip/hip_runtime.h>
#include <math.h>

// B=64, C=1, H=512, W=512 fp32.
// score[b] = cov(x1,x2) / sqrt((v1+eps)*(v2+eps)) per batch plane.
// Two kernels (fusion disproven: R3 __threadfence=serialized buffer_wbl2;
// R5 int64-atomic tree). R8 probe: force 16-deep load clusters with
// __builtin_amdgcn_sched_barrier(0) -- compiler has pinned VGPR=32 and
// serialized loads in every prior round; this is the A/B for issue-depth
// vs DRAM-bound. Null result => ROOFLINE.

#define HW        262144      // 512*512
#define PLANE_F4  65536       // HW/4
#define BPB       16          // blocks per batch plane
#define THREADS   256
#define CHUNK     (PLANE_F4 / BPB)    // 4096 float4 per block per array
#define NBLOCKS   (64 * BPB)          // 1024
#define NBATCH    64
#define EPSN      1e-5

#define ACC(a, c)                                                     \
    s1  += (a.x + a.y) + (a.z + a.w);                                 \
    s2  += (c.x + c.y) + (c.z + c.w);                                 \
    s11 = fmaf(a.x, a.x, s11); s11 = fmaf(a.y, a.y, s11);             \
    s22 = fmaf(c.x, c.x, s22); s22 = fmaf(c.y, c.y, s22);             \
    s11 = fmaf(a.z, a.z, s11); s11 = fmaf(a.w, a.w, s11);             \
    s22 = fmaf(c.z, c.z, s22); s22 = fmaf(c.w, c.w, s22);             \
    s12 = fmaf(a.x, c.x, s12); s12 = fmaf(a.y, c.y, s12);             \
    s12 = fmaf(a.z, c.z, s12); s12 = fmaf(a.w, c.w, s12);

// 16 loads (8 per array) issued as one cluster, then a hard scheduling
// fence, then the 80 FMAs. Forces 16 outstanding loads / 64 live VGPRs.
#define MEGABATCH(k)                                                  \
    {                                                                 \
        const float4 a0 = q1[(8*(k)+0) * THREADS];                    \
        const float4 a1 = q1[(8*(k)+1) * THREADS];                    \
        const float4 a2 = q1[(8*(k)+2) * THREADS];                    \
        const float4 a3 = q1[(8*(k)+3) * THREADS];                    \
        const float4 a4 = q1[(8*(k)+4) * THREADS];                    \
        const float4 a5 = q1[(8*(k)+5) * THREADS];                    \
        const float4 a6 = q1[(8*(k)+6) * THREADS];                    \
        const float4 a7 = q1[(8*(k)+7) * THREADS];                    \
        const float4 c0 = q2[(8*(k)+0) * THREADS];                    \
        const float4 c1 = q2[(8*(k)+1) * THREADS];                    \
        const float4 c2 = q2[(8*(k)+2) * THREADS];                    \
        const float4 c3 = q2[(8*(k)+3) * THREADS];                    \
        const float4 c4 = q2[(8*(k)+4) * THREADS];                    \
        const float4 c5 = q2[(8*(k)+5) * THREADS];                    \
        const float4 c6 = q2[(8*(k)+6) * THREADS];                    \
        const float4 c7 = q2[(8*(k)+7) * THREADS];                    \
        __builtin_amdgcn_sched_barrier(0);                            \
        ACC(a0, c0) ACC(a1, c1) ACC(a2, c2) ACC(a3, c3)               \
        ACC(a4, c4) ACC(a5, c5) ACC(a6, c6) ACC(a7, c7)               \
    }

__global__ __launch_bounds__(THREADS, 4) void xcorr_partial(
        const float4* __restrict__ x1, const float4* __restrict__ x2,
        double* __restrict__ part) {
    const int b  = blockIdx.x >> 4;          // / BPB
    const int jb = blockIdx.x & (BPB - 1);
    const int base = jb * CHUNK + threadIdx.x;
    const float4* q1 = x1 + (long long)b * PLANE_F4 + base;
    const float4* q2 = x2 + (long long)b * PLANE_F4 + base;

    float s1 = 0.f, s2 = 0.f, s11 = 0.f, s22 = 0.f, s12 = 0.f;

    MEGABATCH(0) MEGABATCH(1)    // 16 f4 per array per thread

    // promote to double, wave butterfly then LDS cross-wave (deterministic)
    double d0 = s1, d1 = s2, d2 = s11, d3 = s22, d4 = s12;
    #pragma unroll
    for (int off = 32; off > 0; off >>= 1) {
        d0 += __shfl_down(d0, off, 64);
        d1 += __shfl_down(d1, off, 64);
        d2 += __shfl_down(d2, off, 64);
        d3 += __shfl_down(d3, off, 64);
        d4 += __shfl_down(d4, off, 64);
    }
    __shared__ double lds[4][5];
    const int lane = threadIdx.x & 63;
    const int wv   = threadIdx.x >> 6;
    if (lane == 0) {
        lds[wv][0] = d0; lds[wv][1] = d1; lds[wv][2] = d2;
        lds[wv][3] = d3; lds[wv][4] = d4;
    }
    __syncthreads();
    if (threadIdx.x == 0) {
        // SoA: part[i*NBLOCKS + bid] -> stage-2 loads coalesce
        #pragma unroll
        for (int i = 0; i < 5; ++i)
            part[i * NBLOCKS + blockIdx.x] =
                (lds[0][i] + lds[1][i]) + (lds[2][i] + lds[3][i]);
    }
}

__global__ __launch_bounds__(64) void xcorr_final(
        const double* __restrict__ part, float* __restrict__ out) {
    const int b = blockIdx.x;             // one block per batch
    const int j = threadIdx.x;            // lanes 0..63 (16 carry data)
    const int idx = b * BPB + (j & 15);   // partial index for this batch
    double t0 = 0, t1 = 0, t2 = 0, t3 = 0, t4 = 0;
    if (j < 16) {
        t0 = part[0 * NBLOCKS + idx];
        t1 = part[1 * NBLOCKS + idx];
        t2 = part[2 * NBLOCKS + idx];
        t3 = part[3 * NBLOCKS + idx];
        t4 = part[4 * NBLOCKS + idx];
    }
    #pragma unroll
    for (int off = 8; off > 0; off >>= 1) {    // fixed tree: deterministic
        t0 += __shfl_down(t0, off, 64);
        t1 += __shfl_down(t1, off, 64);
        t2 += __shfl_down(t2, off, 64);
        t3 += __shfl_down(t3, off, 64);
        t4 += __shfl_down(t4, off, 64);
    }
    if (j == 0) {
        const double N  = (double)HW;
        const double m1 = t0 / N, m2 = t1 / N;
        const double v1 = t2 / N - m1 * m1;
        const double v2 = t3 / N - m2 * m2;
        const double cv = t4 / N - m1 * m2;
        out[b] = (float)(cv / sqrt((v1 + EPSN) * (v2 + EPSN)));
    }
}

extern "C" void kernel_launch(void* const* d_in, const int* in_sizes, int n_in,
                              void* d_out, int out_size, void* d_ws, size_t ws_size,
                              hipStream_t stream) {
    const float4* x1 = (const float4*)d_in[0];
    const float4* x2 = (const float4*)d_in[1];
    double* part = (double*)d_ws;          // 5*1024 doubles = 40 KiB, SoA
    float* out = (float*)d_out;

    xcorr_partial<<<NBLOCKS, THREADS, 0, stream>>>(x1, x2, part);
    xcorr_final<<<NBATCH, 64, 0, stream>>>(part, out);
}